// Round 6
// baseline (125.670 us; speedup 1.0000x reference)
//
#include <hip/hip_runtime.h>
#include <hip/hip_bf16.h>

#define BATCH 16
#define CDIM 256
#define NDIM 2048
#define HDIM 128
#define KVB 128
#define NT (NDIM / KVB)

typedef __bf16 bf16;
typedef float f32x4 __attribute__((ext_vector_type(4)));
typedef float f32x16 __attribute__((ext_vector_type(16)));
typedef bf16 bf16x8 __attribute__((ext_vector_type(8)));
typedef unsigned int u32x4 __attribute__((ext_vector_type(4)));
typedef unsigned int u32x2 __attribute__((ext_vector_type(2)));

#define LOG2E 1.4426950408889634f

__device__ __forceinline__ int swz512(int row, int colbyte) {
  return row * 512 + (colbyte ^ ((row & 15) << 4));
}
__device__ __forceinline__ int swz256(int row, int colbyte) {
  return row * 256 + (colbyte ^ ((row & 7) << 4));
}

__device__ __forceinline__ f32x4 mfma16(bf16x8 a, bf16x8 b, f32x4 c) {
  return __builtin_amdgcn_mfma_f32_16x16x32_bf16(a, b, c, 0, 0, 0);
}
__device__ __forceinline__ f32x16 mfma32(bf16x8 a, bf16x8 b, f32x16 c) {
  return __builtin_amdgcn_mfma_f32_32x32x16_bf16(a, b, c, 0, 0, 0);
}

__device__ __forceinline__ unsigned cvtpk(float lo, float hi) {
  unsigned r;
  asm("v_cvt_pk_bf16_f32 %0, %1, %2" : "=v"(r) : "v"(lo), "v"(hi));
  return r;
}
__device__ __forceinline__ void pswap(unsigned &a, unsigned &b) {
  asm volatile("v_permlane32_swap_b32 %0, %1" : "+v"(a), "+v"(b));
}

__device__ __forceinline__ void gload16(const bf16* g, char* l) {
  __builtin_amdgcn_global_load_lds(
      (const __attribute__((address_space(1))) void*)g,
      (__attribute__((address_space(3))) void*)l, 16, 0, 0);
}

__device__ __forceinline__ bf16x8 cvt8(float4 a, float4 b) {
  bf16x8 o;
  o[0] = (bf16)a.x; o[1] = (bf16)a.y; o[2] = (bf16)a.z; o[3] = (bf16)a.w;
  o[4] = (bf16)b.x; o[5] = (bf16)b.y; o[6] = (bf16)b.z; o[7] = (bf16)b.w;
  return o;
}

// ---------------------------------------------------------------------------
// Kernel 0: pack Wq/Wk/Wv into bf16 MFMA-fragment-blocked layout.
// frag f = (p*8 + ks)*8 + hb : 1 KB, lane-linear (addr = f*1024 + lane*16).
// Content: lane l, elem j -> W[hb*16 + (l&15)][ks*32 + (l>>4)*8 + j].
// ---------------------------------------------------------------------------
__global__ __launch_bounds__(256) void k0_prep(
    const float* __restrict__ Wq, const float* __restrict__ Wk,
    const float* __restrict__ Wv, bf16* __restrict__ blk) {
  int tg = blockIdx.x * 256 + threadIdx.x;
  int f = tg >> 6, l = tg & 63;
  const float* W = (f < 64) ? Wq : (f < 128 ? Wk : Wv);
  int ks = (f >> 3) & 7, hb = f & 7;
  const float* src = W + (size_t)(hb * 16 + (l & 15)) * CDIM + ks * 32 + (l >> 4) * 8;
  float4 v0 = *reinterpret_cast<const float4*>(src);
  float4 v1 = *reinterpret_cast<const float4*>(src + 4);
  *reinterpret_cast<bf16x8*>(blk + f * 512 + l * 8) = cvt8(v0, v1);
}

// ---------------------------------------------------------------------------
// Kernel 1: fused QKV projection. No W staging (blocked-bf16 W read directly
// from L2/L1 as lane-linear dwordx4), xT staged via in-register 4x4 shfl
// transpose (conflict-free b64 writes), ONE barrier total.
// grid 512 = (b:16) x (ntile:32, 64 cols), 256 thr = 4 waves.
// ---------------------------------------------------------------------------
__global__ __launch_bounds__(256, 3) void k1_qkv(
    const float* __restrict__ x, const bf16* __restrict__ blk,
    const float* __restrict__ bq, const float* __restrict__ bk,
    const float* __restrict__ bv,
    bf16* __restrict__ Qo, bf16* __restrict__ Ko, bf16* __restrict__ Vo) {
  __shared__ char xT[32768];  // [64 n][256 c] bf16, 512B rows, swz512

  const int t = threadIdx.x;
  const int l = t & 63;
  const int w = t >> 6;
  const int q = (l >> 4) & 3;
  const int b = blockIdx.x >> 5;
  const int n0 = (blockIdx.x & 31) * 64;

  // Stage xT: lane loads float4 (4 n's, one c); 4x4 shfl transpose within
  // lane groups {l, l^16, l^32, l^48}; write bf16x4 (one n, 4 c's) as b64.
#pragma unroll
  for (int p = 0; p < 16; ++p) {
    int c = w * 64 + p * 4 + q;
    float4 v = *reinterpret_cast<const float4*>(
        x + (size_t)(b * CDIM + c) * NDIM + n0 + (l & 15) * 4);
    float t0 = __shfl_xor(v.x, 16), t1 = __shfl_xor(v.y, 16);
    float t2 = __shfl_xor(v.z, 16), t3 = __shfl_xor(v.w, 16);
    float4 wv;
    if ((q & 1) == 0) wv = make_float4(v.x, t0, v.z, t2);
    else              wv = make_float4(t1, v.y, t3, v.w);
    float s0 = __shfl_xor(wv.x, 32), s1 = __shfl_xor(wv.y, 32);
    float s2 = __shfl_xor(wv.z, 32), s3 = __shfl_xor(wv.w, 32);
    float4 z;
    if ((q & 2) == 0) z = make_float4(wv.x, wv.y, s0, s1);
    else              z = make_float4(s2, s3, wv.z, wv.w);
    u32x2 pk = {cvtpk(z.x, z.y), cvtpk(z.z, z.w)};
    int n = (l & 15) * 4 + q;
    int slot = w * 8 + (p >> 1);
    *reinterpret_cast<u32x2*>(
        xT + n * 512 + ((slot ^ (n & 15)) * 16 + (p & 1) * 8)) = pk;
  }
  __syncthreads();

  const bf16* bq_ = blk;
  const bf16* bk_ = blk + 64 * 512;
  const bf16* bv_ = blk + 128 * 512;

  f32x4 aq[8], ak[8], av[8];
#pragma unroll
  for (int i = 0; i < 8; ++i) {
    aq[i] = f32x4{0.f, 0.f, 0.f, 0.f};
    ak[i] = f32x4{0.f, 0.f, 0.f, 0.f};
    av[i] = f32x4{0.f, 0.f, 0.f, 0.f};
  }

#pragma unroll
  for (int ks = 0; ks < 8; ++ks) {
    bf16x8 a = *reinterpret_cast<const bf16x8*>(
        xT + swz512(w * 16 + (l & 15), ks * 64 + (l >> 4) * 16));
#pragma unroll
    for (int nf = 0; nf < 8; ++nf) {
      bf16x8 wq = *reinterpret_cast<const bf16x8*>(bq_ + (ks * 8 + nf) * 512 + l * 8);
      aq[nf] = mfma16(a, wq, aq[nf]);
      bf16x8 wk = *reinterpret_cast<const bf16x8*>(bk_ + (ks * 8 + nf) * 512 + l * 8);
      ak[nf] = mfma16(a, wk, ak[nf]);
    }
    bf16x8 wv0 = *reinterpret_cast<const bf16x8*>(bv_ + (ks * 8 + w * 2 + 0) * 512 + l * 8);
    bf16x8 wv1 = *reinterpret_cast<const bf16x8*>(bv_ + (ks * 8 + w * 2 + 1) * 512 + l * 8);
#pragma unroll
    for (int nf4 = 0; nf4 < 4; ++nf4) {
      bf16x8 bx = *reinterpret_cast<const bf16x8*>(
          xT + swz512(nf4 * 16 + (l & 15), ks * 64 + (l >> 4) * 16));
      av[nf4] = mfma16(wv0, bx, av[nf4]);
      av[4 + nf4] = mfma16(wv1, bx, av[4 + nf4]);
    }
  }

  // Epilogue: Q,K -> [B][N][H]; V -> [B][H][N]; + bias.
#pragma unroll
  for (int nf = 0; nf < 8; ++nf) {
    int h = nf * 16 + (l & 15);
    float biasq = bq[h], biask = bk[h];
#pragma unroll
    for (int r = 0; r < 4; ++r) {
      int n = n0 + w * 16 + (l >> 4) * 4 + r;
      Qo[(size_t)(b * NDIM + n) * HDIM + h] = (bf16)(aq[nf][r] + biasq);
      Ko[(size_t)(b * NDIM + n) * HDIM + h] = (bf16)(ak[nf][r] + biask);
    }
  }
#pragma unroll
  for (int mf = 0; mf < 2; ++mf)
#pragma unroll
    for (int nf4 = 0; nf4 < 4; ++nf4)
#pragma unroll
      for (int r = 0; r < 4; ++r) {
        int h = w * 32 + mf * 16 + (l >> 4) * 4 + r;
        int n = n0 + nf4 * 16 + (l & 15);
        Vo[(size_t)(b * HDIM + h) * NDIM + n] = (bf16)(av[mf * 4 + nf4][r] + bv[h]);
      }
}

// ---------------------------------------------------------------------------
// Kernel 2: flash attention with q-reuse: 8 waves = 2 q-groups(64 q) x
// 4 kpos-quarters(32). Each kf/vf LDS read feeds 2 MFMAs -> LDS reads
// halved per q. KVB=128 (256B rows both tiles, conflict-free), dbuf 128 KB,
// global_load_lds + counted vmcnt(8), max-free softmax, in-register P,
// split-k-4 tree merge. grid 256 (XCD-pinned), 512 thr.
// ---------------------------------------------------------------------------
__global__ __launch_bounds__(512, 1) void k2_attn(
    const bf16* __restrict__ Q, const bf16* __restrict__ K,
    const bf16* __restrict__ V, bf16* __restrict__ O) {
  extern __shared__ char lds[];
  // buf0 @0, buf1 @65536; each: Kt [128 kpos][256B] @0, Vt [128 d][256B] @32768

  const int t = threadIdx.x;
  const int l = t & 63;
  const int w = t >> 6;     // 0..7
  const int wm = w & 1;     // q 64-group
  const int wk = w >> 1;    // kpos quarter (32 kpos)
  const int hi = l >> 5;
  const int c31 = l & 31;

  const int pid = blockIdx.x;
  const int b = (pid & 7) * 2 + ((pid >> 3) >> 4);
  const int q0 = ((pid >> 3) & 15) * 128;

  // Q fragments (B-operand) for the wave's two q-subtiles (issued first).
  bf16x8 qf0[8], qf1[8];
  {
    const bf16* qb = Q + ((size_t)b * NDIM + q0 + wm * 64 + c31) * HDIM + hi * 8;
#pragma unroll
    for (int cs = 0; cs < 8; ++cs) {
      qf0[cs] = *reinterpret_cast<const bf16x8*>(qb + cs * 16);
      qf1[cs] = *reinterpret_cast<const bf16x8*>(qb + 32 * HDIM + cs * 16);
    }
  }

  // Staging: thread covers rows (w*4 + l>>4) + i*32, slot l&15 for K and V.
  // Linear LDS dest (uniform + lane*16); XOR swizzle folded into global src.
  const int srow = w * 4 + (l >> 4);
  const int slot = l & 15;
  unsigned offK[4], offV[4];
#pragma unroll
  for (int i = 0; i < 4; ++i) {
    int r = srow + i * 32;
    offK[i] = (unsigned)((b * NDIM + r) * HDIM + (slot ^ (r & 15)) * 8);
    offV[i] = (unsigned)((b * HDIM + r) * NDIM + (slot ^ (r & 15)) * 8);
  }
  const int kdst = w * 1024;           // + i*8192 (+ lane*16 by HW)
  const int vdst = 32768 + w * 1024;

  f32x16 oacc0[4], oacc1[4];
#pragma unroll
  for (int dg = 0; dg < 4; ++dg)
#pragma unroll
    for (int r = 0; r < 16; ++r) { oacc0[dg][r] = 0.f; oacc1[dg][r] = 0.f; }
  float l0 = 0.f, l1 = 0.f;

  // prologue: tile 0
#pragma unroll
  for (int i = 0; i < 4; ++i) gload16(K + offK[i], lds + kdst + i * 8192);
#pragma unroll
  for (int i = 0; i < 4; ++i) gload16(V + offV[i], lds + vdst + i * 8192);

  const int rx = c31 & 15;

#pragma unroll 1
  for (int kt = 0; kt < NT; ++kt) {
    char* buf = lds + (kt & 1) * 65536;
    if (kt + 1 < NT) {
      char* nbuf = lds + ((kt + 1) & 1) * 65536;
#pragma unroll
      for (int i = 0; i < 4; ++i) {
        offK[i] += (unsigned)(KVB * HDIM);
        gload16(K + offK[i], nbuf + kdst + i * 8192);
      }
#pragma unroll
      for (int i = 0; i < 4; ++i) {
        offV[i] += (unsigned)KVB;
        gload16(V + offV[i], nbuf + vdst + i * 8192);
      }
      asm volatile("s_waitcnt vmcnt(8)" ::: "memory");  // tile kt landed
    } else {
      asm volatile("s_waitcnt vmcnt(0)" ::: "memory");
    }
    __builtin_amdgcn_s_barrier();

    const char* Kt = buf;
    const char* Vt = buf + 32768;

    // S^T = mfma(K, Q) for both q-groups; kf read once, used twice.
    f32x16 s0, s1;
#pragma unroll
    for (int r = 0; r < 16; ++r) { s0[r] = 0.f; s1[r] = 0.f; }
    __builtin_amdgcn_s_setprio(1);
    {
      const char* kr = Kt + (wk * 32 + c31) * 256;
#pragma unroll
      for (int cs = 0; cs < 8; ++cs) {
        bf16x8 kf = *reinterpret_cast<const bf16x8*>(
            kr + (((cs * 2 + hi) ^ rx) * 16));
        s0 = mfma32(kf, qf0[cs], s0);
        s1 = mfma32(kf, qf1[cs], s1);
      }
    }
    __builtin_amdgcn_s_setprio(0);

    // Max-free softmax + in-register P->bf16, per q-group.
    bf16x8 pa0[2], pa1[2];
#pragma unroll
    for (int qs = 0; qs < 2; ++qs) {
      f32x16& s = qs ? s1 : s0;
      float sum = 0.f;
#pragma unroll
      for (int r = 0; r < 16; ++r) {
        float p = __builtin_amdgcn_exp2f(s[r] * LOG2E);
        s[r] = p;
        sum += p;
      }
      if (qs) l1 += sum; else l0 += sum;
      unsigned w0 = cvtpk(s[0], s[1]);
      unsigned w1 = cvtpk(s[2], s[3]);
      unsigned w2 = cvtpk(s[4], s[5]);
      unsigned w3 = cvtpk(s[6], s[7]);
      unsigned w4 = cvtpk(s[8], s[9]);
      unsigned w5 = cvtpk(s[10], s[11]);
      unsigned w6 = cvtpk(s[12], s[13]);
      unsigned w7 = cvtpk(s[14], s[15]);
      pswap(w0, w2); pswap(w1, w3); pswap(w4, w6); pswap(w5, w7);
      u32x4 pw0 = {w0, w1, w2, w3};
      u32x4 pw1 = {w4, w5, w6, w7};
      (qs ? pa1 : pa0)[0] = __builtin_bit_cast(bf16x8, pw0);
      (qs ? pa1 : pa0)[1] = __builtin_bit_cast(bf16x8, pw1);
    }

    // PV: vf read once, used for both q-groups.
    __builtin_amdgcn_s_setprio(1);
#pragma unroll
    for (int ks = 0; ks < 2; ++ks) {
#pragma unroll
      for (int dg = 0; dg < 4; ++dg) {
        const char* vr = Vt + (dg * 32 + c31) * 256;
        bf16x8 vf = *reinterpret_cast<const bf16x8*>(
            vr + (((wk * 4 + ks * 2 + hi) ^ rx) * 16));
        oacc0[dg] = mfma32(pa0[ks], vf, oacc0[dg]);
        oacc1[dg] = mfma32(pa1[ks], vf, oacc1[dg]);
      }
    }
    __builtin_amdgcn_s_setprio(0);
    __builtin_amdgcn_s_barrier();  // all waves done reading buf
  }

  // ---- split-k-4 merge. Tile buffers dead; regions idx*32KB (128 KB).
  l0 += __shfl_xor(l0, 32);
  l1 += __shfl_xor(l1, 32);
  float* Ls = (float*)(lds + 131072);  // [wm][qs][wk][32]
  if (l < 32) {
    Ls[((wm * 2 + 0) * 4 + wk) * 32 + c31] = l0;
    Ls[((wm * 2 + 1) * 4 + wk) * 32 + c31] = l1;
  }
  auto region = [&](int idx) { return (float*)(lds + idx * 32768); };
  if (wk & 1) {  // wk 1,3 write
    float* R = region(wm * 2 + (wk >> 1));
#pragma unroll
    for (int dg = 0; dg < 4; ++dg)
#pragma unroll
      for (int r = 0; r < 16; ++r) {
        R[((0 * 4 + dg) * 16 + r) * 64 + l] = oacc0[dg][r];
        R[((1 * 4 + dg) * 16 + r) * 64 + l] = oacc1[dg][r];
      }
  }
  __syncthreads();
  if (!(wk & 1)) {  // wk 0,2 accumulate
    float* R = region(wm * 2 + (wk >> 1));
#pragma unroll
    for (int dg = 0; dg < 4; ++dg)
#pragma unroll
      for (int r = 0; r < 16; ++r) {
        oacc0[dg][r] += R[((0 * 4 + dg) * 16 + r) * 64 + l];
        oacc1[dg][r] += R[((1 * 4 + dg) * 16 + r) * 64 + l];
      }
  }
  __syncthreads();
  if (wk == 2) {
    float* R = region(wm);
#pragma unroll
    for (int dg = 0; dg < 4; ++dg)
#pragma unroll
      for (int r = 0; r < 16; ++r) {
        R[((0 * 4 + dg) * 16 + r) * 64 + l] = oacc0[dg][r];
        R[((1 * 4 + dg) * 16 + r) * 64 + l] = oacc1[dg][r];
      }
  }
  __syncthreads();
  if (wk == 0) {
    float* R = region(wm);
    float linv0, linv1;
    {
      int base0 = (wm * 2 + 0) * 4 * 32 + c31;
      int base1 = (wm * 2 + 1) * 4 * 32 + c31;
      linv0 = 1.0f / (Ls[base0] + Ls[base0 + 32] + Ls[base0 + 64] + Ls[base0 + 96]);
      linv1 = 1.0f / (Ls[base1] + Ls[base1 + 32] + Ls[base1 + 64] + Ls[base1 + 96]);
    }
    int ib0 = __builtin_bit_cast(int, linv0);
    int ib1 = __builtin_bit_cast(int, linv1);
#pragma unroll
    for (int dg = 0; dg < 4; ++dg) {
      int h = dg * 32 + c31;
#pragma unroll
      for (int r = 0; r < 16; ++r) {
        int crow = (r & 3) + 8 * (r >> 2) + 4 * hi;
        float f0 = __builtin_bit_cast(
            float, __builtin_amdgcn_ds_bpermute(crow * 4, ib0));
        float f1 = __builtin_bit_cast(
            float, __builtin_amdgcn_ds_bpermute(crow * 4, ib1));
        float v0 = (oacc0[dg][r] + R[((0 * 4 + dg) * 16 + r) * 64 + l]) * f0;
        float v1 = (oacc1[dg][r] + R[((1 * 4 + dg) * 16 + r) * 64 + l]) * f1;
        int n_0 = q0 + wm * 64 + crow;
        O[((size_t)b * NDIM + n_0) * HDIM + h] = (bf16)v0;
        O[((size_t)b * NDIM + n_0 + 32) * HDIM + h] = (bf16)v1;
      }
    }
  }
}

// ---------------------------------------------------------------------------
// Kernel 3: out = Wf @ O + bf + x (unchanged; near HBM roofline)
// ---------------------------------------------------------------------------
__global__ __launch_bounds__(256) void k3_proj(
    const bf16* __restrict__ O, const float* __restrict__ Wf,
    const float* __restrict__ bfv, const float* __restrict__ x,
    float* __restrict__ out) {
  __shared__ char lds[49152];
  char* Wt = lds;
  char* Ot = lds + 32768;

  const int t = threadIdx.x;
  const int l = t & 63;
  const int w = t >> 6;
  const int b = blockIdx.x >> 5;
  const int n0 = (blockIdx.x & 31) * 64;

#pragma unroll
  for (int pass = 0; pass < 4; ++pass) {
    int n = pass * 16 + (t >> 4);
    int hq = t & 15;
    uint4 d = *reinterpret_cast<const uint4*>(
        O + (size_t)(b * NDIM + n0 + n) * HDIM + hq * 8);
    *reinterpret_cast<uint4*>(Ot + swz256(n, hq * 16)) = d;
  }

#pragma unroll 1
  for (int ch = 0; ch < 2; ++ch) {
    __syncthreads();
#pragma unroll
    for (int pass = 0; pass < 8; ++pass) {
      int cl = pass * 16 + (t >> 4);
      int hq = t & 15;
      const float* src = Wf + (size_t)(ch * 128 + cl) * HDIM + hq * 8;
      float4 v0 = *reinterpret_cast<const float4*>(src);
      float4 v1 = *reinterpret_cast<const float4*>(src + 4);
      *reinterpret_cast<bf16x8*>(Wt + swz256(cl, hq * 16)) = cvt8(v0, v1);
    }
    __syncthreads();

    f32x4 acc[2][4];
#pragma unroll
    for (int i = 0; i < 2; ++i)
#pragma unroll
      for (int j = 0; j < 4; ++j) acc[i][j] = f32x4{0.f, 0.f, 0.f, 0.f};

#pragma unroll
    for (int ks = 0; ks < 4; ++ks) {
      int cb = ks * 64 + (l >> 4) * 16;
      bf16x8 a0 = *reinterpret_cast<const bf16x8*>(
          Wt + swz256(w * 32 + (l & 15), cb));
      bf16x8 a1 = *reinterpret_cast<const bf16x8*>(
          Wt + swz256(w * 32 + 16 + (l & 15), cb));
#pragma unroll
      for (int nf = 0; nf < 4; ++nf) {
        bf16x8 bb = *reinterpret_cast<const bf16x8*>(
            Ot + swz256(nf * 16 + (l & 15), cb));
        acc[0][nf] = mfma16(a0, bb, acc[0][nf]);
        acc[1][nf] = mfma16(a1, bb, acc[1][nf]);
      }
    }

#pragma unroll
    for (int mf = 0; mf < 2; ++mf)
#pragma unroll
      for (int nf = 0; nf < 4; ++nf)
#pragma unroll
        for (int r = 0; r < 4; ++r) {
          int c = ch * 128 + w * 32 + mf * 16 + (l >> 4) * 4 + r;
          int n = n0 + nf * 16 + (l & 15);
          size_t idx = (size_t)(b * CDIM + c) * NDIM + n;
          out[idx] = acc[mf][nf][r] + bfv[c] + x[idx];
        }
  }
}

extern "C" void kernel_launch(void* const* d_in, const int* in_sizes, int n_in,
                              void* d_out, int out_size, void* d_ws,
                              size_t ws_size, hipStream_t stream) {
  (void)in_sizes; (void)n_in;
  const float* x = (const float*)d_in[0];
  const float* Wq = (const float*)d_in[1];
  const float* bq = (const float*)d_in[2];
  const float* Wk = (const float*)d_in[3];
  const float* bk = (const float*)d_in[4];
  const float* Wv = (const float*)d_in[5];
  const float* bv = (const float*)d_in[6];
  const float* Wf = (const float*)d_in[7];
  const float* bfv = (const float*)d_in[8];
  float* out = (float*)d_out;

  if (ws_size < (24u << 20)) return;
  char* ws = (char*)d_ws;
  bf16* Qb = (bf16*)(ws);                  // 8 MB [B][N][H]; reused as O
  bf16* Kb = (bf16*)(ws + (8u << 20));     // 8 MB [B][N][H]
  bf16* Vb = (bf16*)(ws + (16u << 20));    // 8 MB [B][H][N]

  // Blocked-bf16 W lives in d_out's tail (k3 overwrites it afterwards).
  const size_t out_bytes = (size_t)out_size * 4;
  bf16* Wblk = (bf16*)((char*)d_out + out_bytes - 196608);

  const unsigned k2_lds = 133120;  // 2x64KB dbuf + 2KB Ls (merge reuses dbuf)
  hipFuncSetAttribute(reinterpret_cast<const void*>(k2_attn),
                      hipFuncAttributeMaxDynamicSharedMemorySize, (int)k2_lds);

  k0_prep<<<48, 256, 0, stream>>>(Wq, Wk, Wv, Wblk);
  k1_qkv<<<512, 256, 0, stream>>>(x, Wblk, bq, bk, bv, Qb, Kb, Vb);
  k2_attn<<<256, 512, k2_lds, stream>>>(Qb, Kb, Vb, Qb);
  k3_proj<<<512, 256, 0, stream>>>(Qb, Wf, bfv, x, out);
}